// Round 6
// baseline (3624.809 us; speedup 1.0000x reference)
//
#include <hip/hip_runtime.h>

#define TT 1024
#define HH 256
#define EE 64
#define NC 10
#define SCA __HIP_MEMORY_SCOPE_AGENT

// 256 blocks = 128 rows x 2 j-halves (pair (bid, bid+128) lands on same XCD).
// 1024 threads: jloc = tid>>3 (0..127), ks = tid&7 (k-slice of 16 per phase).
// Per-thread weights = 128 f32 (invariant: 512KB block / 1024 thr). Split:
//   f,i,g (96) in VGPRs -- fits the 128-reg cap at 4 waves/EU with no AGPR
//   moves (R5 lesson: 192/thread forced a 128/128 arch/acc split = +40% VALU).
//   o (32) in LDS lane-linear (128KB, conflict-free b128).
// h buffers padded k + (k>>4)*4: 8 broadcast addrs -> 8 distinct banks
// (unpadded was a 4-way conflict: ks*16 mod 32 hits only 2 banks).
// Cross-CU: R5's proven relaxed-scoped-atomic flag + L3 h exchange, with the
// peer-half load issued before PHASE(0) so L3 latency hides under own-half FMA.

#define PHASE(P, HB)                                                         \
  do {                                                                       \
    _Pragma("unroll")                                                        \
    for (int s = 0; s < 4; ++s) {                                            \
      const float4 hv = *(const float4*)((HB) + ks20 + s * 4);               \
      const float4 wo4 = *(const float4*)(wo_base + ((P) * 4 + s) * 256);    \
      af = fmaf(hv.x, wf[(P) * 16 + s * 4 + 0], af);                         \
      af = fmaf(hv.y, wf[(P) * 16 + s * 4 + 1], af);                         \
      af = fmaf(hv.z, wf[(P) * 16 + s * 4 + 2], af);                         \
      af = fmaf(hv.w, wf[(P) * 16 + s * 4 + 3], af);                         \
      ai = fmaf(hv.x, wi[(P) * 16 + s * 4 + 0], ai);                         \
      ai = fmaf(hv.y, wi[(P) * 16 + s * 4 + 1], ai);                         \
      ai = fmaf(hv.z, wi[(P) * 16 + s * 4 + 2], ai);                         \
      ai = fmaf(hv.w, wi[(P) * 16 + s * 4 + 3], ai);                         \
      ag = fmaf(hv.x, wg[(P) * 16 + s * 4 + 0], ag);                         \
      ag = fmaf(hv.y, wg[(P) * 16 + s * 4 + 1], ag);                         \
      ag = fmaf(hv.z, wg[(P) * 16 + s * 4 + 2], ag);                         \
      ag = fmaf(hv.w, wg[(P) * 16 + s * 4 + 3], ag);                         \
      ao = fmaf(hv.x, wo4.x, ao);                                            \
      ao = fmaf(hv.y, wo4.y, ao);                                            \
      ao = fmaf(hv.z, wo4.z, ao);                                            \
      ao = fmaf(hv.w, wo4.w, ao);                                            \
    }                                                                        \
  } while (0)

__global__ __launch_bounds__(1024, 4) void lstm_pair8(
    const int* __restrict__ x, const float* __restrict__ emb,
    const float* __restrict__ Wfx, const float* __restrict__ Wfh, const float* __restrict__ bf_,
    const float* __restrict__ Wix, const float* __restrict__ Wih, const float* __restrict__ bi_,
    const float* __restrict__ Wgx, const float* __restrict__ Wgh, const float* __restrict__ bg_,
    const float* __restrict__ Wox, const float* __restrict__ Woh, const float* __restrict__ bo_,
    const float* __restrict__ Wph, const float* __restrict__ Wpb,
    unsigned int* __restrict__ flags, float* __restrict__ hx,
    float* __restrict__ out)
{
  const int tid  = threadIdx.x;
  const int bid  = blockIdx.x;
  const int row  = bid & 127;
  const int hf   = bid >> 7;
  const int jloc = tid >> 3;            // 0..127
  const int ks   = tid & 7;             // k-slice
  const int ks20 = ks * 20;             // padded h base (stride 20 per 16 k)
  const int jglob = hf * 128 + jloc;
  const int wv = tid >> 6, lane = tid & 63;
  const int kb_own  = hf * 128;
  const int kb_peer = 128 - hf * 128;

  __shared__ __align__(16) float wo_l[32768];   // [wv][chunk 0..7][lane][4]
  __shared__ __align__(16) float hbufA[160];    // padded: idx k + (k>>4)*4
  __shared__ __align__(16) float hbufB[160];
  __shared__ __align__(16) float hpeer[160];
  __shared__ float xp[1536];                    // [v][gate][jloc], bias folded
  __shared__ int   xs[TT];
  __shared__ float pj[NC];

  unsigned int* myflag = flags + (row * 2 + hf) * 32;
  unsigned int* pflag  = flags + (row * 2 + (1 - hf)) * 32;

  xs[tid] = x[row * TT + tid];

  // x-projection: 3 vocab x 4 gates x 128 local cols (fp32 exact)
  for (int idx = tid; idx < 1536; idx += 1024) {
    int v = idx >> 9, r = idx & 511, g = r >> 7, jl = r & 127;
    const float* Wx = (g == 0) ? Wfx : (g == 1) ? Wix : (g == 2) ? Wgx : Wox;
    const float* bb = (g == 0) ? bf_ : (g == 1) ? bi_ : (g == 2) ? bg_ : bo_;
    float a = bb[hf * 128 + jl];
    const float* ev = emb + v * EE;
#pragma unroll 16
    for (int e = 0; e < EE; ++e) a = fmaf(ev[e], Wx[e * HH + hf * 128 + jl], a);
    xp[idx] = a;
  }

  // weights: chunks 0..3 = own k-half slice, 4..7 = peer k-half slice
  float wf[32], wi[32], wg[32];
  float* wo_base = &wo_l[(wv * 8) * 256 + lane * 4];
#pragma unroll
  for (int c = 0; c < 8; ++c) {
    const int p = c >> 2, su = c & 3;
#pragma unroll
    for (int e = 0; e < 4; ++e) {
      const int k = (p ? kb_peer : kb_own) + ks * 16 + su * 4 + e;
      const int r = p * 16 + su * 4 + e;
      wf[r] = Wfh[k * HH + jglob];
      wi[r] = Wih[k * HH + jglob];
      wg[r] = Wgh[k * HH + jglob];
      wo_l[(wv * 8 + c) * 256 + lane * 4 + e] = Woh[k * HH + jglob];
    }
  }

  if (tid < 160) { hbufA[tid] = 0.f; hbufB[tid] = 0.f; }
  float creg = 0.f;
  __syncthreads();

  for (int t = 0; t < TT; ++t) {
    const int rb = t & 1;
    const float* hR = rb ? hbufB : hbufA;   // own h(t-1)
    float* hW       = rb ? hbufA : hbufB;

    if (tid == 0) {
      while (__hip_atomic_load(pflag, __ATOMIC_RELAXED, SCA) < (unsigned)t) { }
    }
    __syncthreads();               // B1: peer h(t-1) at coherence point

    float pv = 0.f;                // issue peer-half load; hides under PHASE(0)
    if (tid < 128)
      pv = __hip_atomic_load(&hx[(((rb ^ 1) * 128 + row) * 2 + (1 - hf)) * 128 + tid],
                             __ATOMIC_RELAXED, SCA);

    float af = 0.f, ai = 0.f, ag = 0.f, ao = 0.f;
    PHASE(0, hR);                  // own k-slice from local LDS

    if (tid < 128) hpeer[tid + ((tid >> 4) << 2)] = pv;
    __syncthreads();               // B2: hpeer staged

    PHASE(1, hpeer);               // peer k-slice

    af += __shfl_xor(af, 1, 64); af += __shfl_xor(af, 2, 64); af += __shfl_xor(af, 4, 64);
    ai += __shfl_xor(ai, 1, 64); ai += __shfl_xor(ai, 2, 64); ai += __shfl_xor(ai, 4, 64);
    ag += __shfl_xor(ag, 1, 64); ag += __shfl_xor(ag, 2, 64); ag += __shfl_xor(ag, 4, 64);
    ao += __shfl_xor(ao, 1, 64); ao += __shfl_xor(ao, 2, 64); ao += __shfl_xor(ao, 4, 64);

    {
      const int v = xs[t];
      const float* xb = xp + v * 512 + jloc;
      float pf = af + xb[0];
      float pi = ai + xb[128];
      float pg = ag + xb[256];
      float po = ao + xb[384];
      float f  = __fdividef(1.f, 1.f + __expf(-pf));
      float i2 = __fdividef(1.f, 1.f + __expf(-pi));
      float o  = __fdividef(1.f, 1.f + __expf(-po));
      float gx = fminf(15.f, fmaxf(-15.f, pg));
      float eg = __expf(2.f * gx);
      float g  = __fdividef(eg - 1.f, eg + 1.f);
      creg = f * creg + i2 * g;
      float cx = fminf(15.f, fmaxf(-15.f, creg));
      float ec = __expf(2.f * cx);
      float th = __fdividef(ec - 1.f, ec + 1.f);
      float hval = th * o;
      if (ks == 0) {
        hW[jloc + ((jloc >> 4) << 2)] = hval;
        __hip_atomic_store(&hx[((rb * 128 + row) * 2 + hf) * 128 + jloc],
                           hval, __ATOMIC_RELAXED, SCA);
      }
    }
    __syncthreads();               // B3: drains all scoped h stores
    if (tid == 0)
      __hip_atomic_fetch_add(myflag, 1u, __ATOMIC_RELAXED, SCA);
  }

  // ---- final projection + log_softmax on half-0 blocks ----
  if (hf != 0) return;
  if (tid == 0) {
    while (__hip_atomic_load(pflag, __ATOMIC_RELAXED, SCA) < (unsigned)TT) { }
  }
  __syncthreads();
  if (tid < 128) {                 // peer final half: t=1023 stored slot rb=1
    float pv = __hip_atomic_load(&hx[((1 * 128 + row) * 2 + 1) * 128 + tid],
                                 __ATOMIC_RELAXED, SCA);
    hpeer[tid + ((tid >> 4) << 2)] = pv;
  }
  __syncthreads();
  if (tid < NC) {                  // own final half in hbufA (t=1023 wrote A)
    float a = Wpb[tid];
    for (int k = 0; k < 128; ++k)
      a = fmaf(hbufA[k + ((k >> 4) << 2)], Wph[k * NC + tid], a);
    for (int k = 0; k < 128; ++k)
      a = fmaf(hpeer[k + ((k >> 4) << 2)], Wph[(128 + k) * NC + tid], a);
    pj[tid] = a;
  }
  __syncthreads();
  if (tid < NC) {
    float m = pj[0];
#pragma unroll
    for (int c2 = 1; c2 < NC; ++c2) m = fmaxf(m, pj[c2]);
    float s = 0.f;
#pragma unroll
    for (int c2 = 0; c2 < NC; ++c2) s += __expf(pj[c2] - m);
    out[row * NC + tid] = pj[tid] - m - __logf(s);
  }
}

extern "C" void kernel_launch(void* const* d_in, const int* in_sizes, int n_in,
                              void* d_out, int out_size, void* d_ws, size_t ws_size,
                              hipStream_t stream) {
  (void)in_sizes; (void)n_in; (void)out_size; (void)ws_size;
  const int*   x   = (const int*)d_in[0];
  const float* emb = (const float*)d_in[1];
  const float* Wfx = (const float*)d_in[2];
  const float* Wfh = (const float*)d_in[3];
  const float* bf_ = (const float*)d_in[4];
  const float* Wix = (const float*)d_in[5];
  const float* Wih = (const float*)d_in[6];
  const float* bi_ = (const float*)d_in[7];
  const float* Wgx = (const float*)d_in[8];
  const float* Wgh = (const float*)d_in[9];
  const float* bg_ = (const float*)d_in[10];
  const float* Wox = (const float*)d_in[11];
  const float* Woh = (const float*)d_in[12];
  const float* bo_ = (const float*)d_in[13];
  const float* Wph = (const float*)d_in[14];
  const float* Wpb = (const float*)d_in[15];

  unsigned int* flags = (unsigned int*)d_ws;
  float*        hx    = (float*)((char*)d_ws + 32768);

  // zero flags + both hx slots (h(-1)=0); captured -> runs on every replay
  hipMemsetAsync(d_ws, 0, 32768 + 262144, stream);

  hipLaunchKernelGGL(lstm_pair8, dim3(256), dim3(1024), 0, stream,
      x, emb, Wfx, Wfh, bf_, Wix, Wih, bi_, Wgx, Wgh, bg_, Wox, Woh, bo_,
      Wph, Wpb, flags, hx, (float*)d_out);
}